// Round 7
// baseline (2397.042 us; speedup 1.0000x reference)
//
#include <hip/hip_runtime.h>

typedef short bf16x8 __attribute__((ext_vector_type(8)));
typedef float f32x4 __attribute__((ext_vector_type(4)));
typedef float f32x2 __attribute__((ext_vector_type(2)));
typedef unsigned short u16;
typedef unsigned int u32;
typedef unsigned long long u64;

#define NPTS 16384
#define NPOINT 1024
#define STOT 524288   // 16*1024*32 samples
#define NCB 240       // conv blocks (blocks 16..255)
#define NW  960       // conv workers (4-wave groups)

__device__ __forceinline__ u16 f2bf(float f){
  u32 u = __builtin_bit_cast(u32, f);
  u += 0x7fffu + ((u >> 16) & 1u);
  return (u16)(u >> 16);
}
__device__ __forceinline__ float bf2f(u16 u){
  u32 x = ((u32)u) << 16;
  return __builtin_bit_cast(float, x);
}

// f32 max-combine across lanes via DPP (1-2 VALU insts per level).
template<int CTRL>
__device__ __forceinline__ float dpp_maxf(float v){
  int x = __builtin_amdgcn_update_dpp(0, __builtin_bit_cast(int, v), CTRL, 0xf, 0xf, true);
  return fmaxf(v, __builtin_bit_cast(float, x));
}
// 64-bit max-combine across lanes via DPP (exact keys).
template<int CTRL>
__device__ __forceinline__ u64 dpp_max(u64 key){
  u32 lo = (u32)key, hi = (u32)(key >> 32);
  u32 lo1 = (u32)__builtin_amdgcn_update_dpp(0, (int)lo, CTRL, 0xf, 0xf, true);
  u32 hi1 = (u32)__builtin_amdgcn_update_dpp(0, (int)hi, CTRL, 0xf, 0xf, true);
  u64 k1 = ((u64)hi1 << 32) | (u64)lo1;
  return (k1 > key) ? k1 : key;
}
__device__ __forceinline__ u64 packkey(float d, int idx){
  // d >= 0 so uint order on float bits == float order; ~idx -> ties pick smaller idx
  return ((u64)__builtin_bit_cast(u32, d) << 32) | (u64)(u32)(~(u32)idx);
}

__device__ __forceinline__ void arrive(u32* c){
  __hip_atomic_fetch_add(c, 1u, __ATOMIC_RELEASE, __HIP_MEMORY_SCOPE_AGENT);
}
__device__ __forceinline__ void waitc(u32* c, u32 tgt){
  while (__hip_atomic_load(c, __ATOMIC_ACQUIRE, __HIP_MEMORY_SCOPE_AGENT) < tgt)
    __builtin_amdgcn_s_sleep(16);
}

// FPS LDS (r6 lesson: coords stay in REGISTERS — LDS-resident coords put the
// distance loop on the single LDS pipe, ~3000cy/iter. r0/r5 lesson: barrier
// count 2->1 changed nothing -> suspect lockstep convoy cost; this round
// replaces per-iter barriers with data-flow tag polling):
//   kx/ky/kz/klo/khi[8][16]: SoA winner records, ring of 8 slots (4B stride,
//     conflict-free). klo/khi = exact u64 (dist,~idx) key.
//   wseq[8][16]: per-slot tags, release-stored AFTER the record; consumers
//     acquire-poll all 16 == it. Slot<->iteration unique within an 8-group;
//     __syncthreads() every 8 iters prevents reuse hazard. Tags init 0xFFFFFFFF.
//   cbuf: centers, bulk-dumped post-loop.
struct FpsS  {
  float cbuf[NPOINT][3];
  float kx[8][16], ky[8][16], kz[8][16];
  u32 klo[8][16], khi[8][16];
  u32 wseq[8][16];
};
struct ConvS { float lsum[128]; float lsqr[128]; float av[128]; float dv[128]; };
union SMemU  { FpsS fps; ConvS conv; };

__device__ __forceinline__ bf16x8 load_bn_relu(const u16* __restrict__ row, int ko,
                                               const float* __restrict__ av,
                                               const float* __restrict__ dv){
  uint4 r = *(const uint4*)(row + ko);
  u32 w[4] = {r.x, r.y, r.z, r.w};
  bf16x8 out;
#pragma unroll
  for (int jj = 0; jj < 8; jj++){
    u16 us = (u16)(w[jj >> 1] >> ((jj & 1) * 16));
    float h = fmaxf(fmaf(av[ko + jj], bf2f(us), dv[ko + jj]), 0.f);
    out[jj] = (short)f2bf(h);
  }
  return out;
}

// zero the sync counters (ws is re-poisoned 0xAA before every call)
__global__ void zero_kernel(u32* __restrict__ ctrs){
  if (threadIdx.x < 64) ctrs[threadIdx.x] = 0;
}

// ================================================================ MEGA KERNEL
// blocks 0..15  : FPS — 16 waves, all coords in registers (r0 core). ZERO
//                 global ops in the loop. NO per-iter barrier: winner lane of
//                 each wave writes its record + release-tag to ring slot it&7;
//                 all waves acquire-poll the 16 tags, then 4-level u64 DPP over
//                 the exact keys (unique -> branchless) + readlane recovers the
//                 winner's coords. __syncthreads() only every 8 iterations.
// blocks 16..255: persistent conv chain (phases via device-scope counters).
// Cross-block per-iter sync banned (r1: ~16k cy). Center broadcast must be
// on-chip (r2: global re-load = +1050cy HBM miss under conv traffic).
__global__ __launch_bounds__(1024, 4) void mega_kernel(
    const float* __restrict__ xyz, const float* __restrict__ points,
    const int* __restrict__ finit, const int* __restrict__ gidx,
    const float* __restrict__ W0, const float* __restrict__ g0v, const float* __restrict__ be0,
    const float* __restrict__ W1, const float* __restrict__ g1v, const float* __restrict__ be1,
    const float* __restrict__ W2, const float* __restrict__ g2v, const float* __restrict__ be2,
    float* __restrict__ out0, float* __restrict__ out1,
    u16* __restrict__ XP, u16* __restrict__ y0, u16* __restrict__ y1,
    float* __restrict__ maxb, float* __restrict__ minb,
    float* __restrict__ statsF,
    u16* __restrict__ W0bf, u16* __restrict__ W1bf, u16* __restrict__ W2bf,
    u32* __restrict__ ctrs){
  __shared__ SMemU sm;
  const int t = threadIdx.x;
  const int wave = t >> 6, lane = t & 63;

  if (blockIdx.x < 16){
    // ------------------------------------------------------------ FPS path
    const int b = blockIdx.x;
    const float* xb = xyz + (size_t)b * 3 * NPTS;
    f32x2 px[8], py[8], pz[8], dist[8];
#pragma unroll
    for (int j = 0; j < 8; j++){
      f32x2 x, y, z;
#pragma unroll
      for (int h = 0; h < 2; h++){
        int n = ((2*j + h) << 10) + t;
        x[h] = xb[n];
        y[h] = xb[NPTS + n];
        z[h] = xb[2*NPTS + n];
      }
      px[j] = x; py[j] = y; pz[j] = z;
      f32x2 big = {1e10f, 1e10f};
      dist[j] = big;
    }
    // init ring tags (never equal to a valid it < 1024)
    if (t < 128) sm.fps.wseq[t >> 4][t & 15] = 0xFFFFFFFFu;
    // initial center: one-time uniform loads (retire before first use)
    const int far0 = finit[b];
    float ccx = xb[far0], ccy = xb[NPTS + far0], ccz = xb[2*NPTS + far0];
    __syncthreads();

    for (int it = 0; it < NPOINT; it++){
      const int s = it & 7;
      if (t == 0){
        sm.fps.cbuf[it][0] = ccx;
        sm.fps.cbuf[it][1] = ccy;
        sm.fps.cbuf[it][2] = ccz;
      }
      float bv = -1.f; int bk = 0;
      {
#pragma clang fp contract(off)
        f32x2 cx2 = {ccx, ccx}, cy2 = {ccy, ccy}, cz2 = {ccz, ccz};
#pragma unroll
        for (int j = 0; j < 8; j++){
          f32x2 dx = px[j] - cx2;
          f32x2 dy = py[j] - cy2;
          f32x2 dz = pz[j] - cz2;
          f32x2 dd = dx*dx + dy*dy + dz*dz;   // matches reference eval order
          f32x2 dm = __builtin_elementwise_min(dist[j], dd);
          dist[j] = dm;
          bool g0 = dm.x > bv;
          bv = g0 ? dm.x : bv;  bk = g0 ? (2*j)   : bk;
          bool g1 = dm.y > bv;
          bv = g1 ? dm.y : bv;  bk = g1 ? (2*j+1) : bk;
        }
      }
      // ---- stage 1: wave max (f32 DPP) + winner-lane identification
      float m = bv;
      m = dpp_maxf<0xB1>(m);   // xor1
      m = dpp_maxf<0x4E>(m);   // xor2
      m = dpp_maxf<0x141>(m);  // half_mirror
      m = dpp_maxf<0x140>(m);  // mirror
      m = dpp_maxf<0x142>(m);  // bcast15
      m = dpp_maxf<0x143>(m);  // bcast31 -> lanes 48-63 hold wave max
      float ms = __builtin_bit_cast(float, __builtin_amdgcn_readlane(__builtin_bit_cast(int, m), 63));
      u64 mk = __ballot(bv == ms);
      int wl;
      if (__popcll(mk) == 1){
        wl = (int)__builtin_ctzll(mk);
      } else {
        // exact-tie fallback: full u64 (dist,~idx) DPP chain -> winner lane
        u64 key = packkey(bv, (bk << 10) + t);
        key = dpp_max<0xB1>(key); key = dpp_max<0x4E>(key);
        key = dpp_max<0x141>(key); key = dpp_max<0x140>(key);
        key = dpp_max<0x142>(key); key = dpp_max<0x143>(key);
        u32 lo = (u32)__builtin_amdgcn_readlane((int)(u32)key, 63);
        wl = (int)((~lo) & 63u);    // winner thread's lane within this wave
      }
      // ---- winner lane publishes record, then release-stores the tag
      if (lane == wl){
        int kk2 = bk;
        float sx = px[0].x, sy = py[0].x, sz = pz[0].x;
#pragma unroll
        for (int k = 1; k < 16; k++){
          bool e = (kk2 == k);
          float vx = px[k>>1][k&1], vy = py[k>>1][k&1], vz = pz[k>>1][k&1];
          sx = e ? vx : sx; sy = e ? vy : sy; sz = e ? vz : sz;
        }
        u64 key = packkey(bv, (bk << 10) + t);
        sm.fps.kx[s][wave] = sx;
        sm.fps.ky[s][wave] = sy;
        sm.fps.kz[s][wave] = sz;
        sm.fps.klo[s][wave] = (u32)key;
        sm.fps.khi[s][wave] = (u32)(key >> 32);
        __hip_atomic_store(&sm.fps.wseq[s][wave], (u32)it,
                           __ATOMIC_RELEASE, __HIP_MEMORY_SCOPE_WORKGROUP);
      }
      if (it < NPOINT - 1){
        // ---- data-flow wait: all 16 tags == it (no barrier)
        const int sl = lane & 15;
        u32 tag;
        do {
          tag = __hip_atomic_load(&sm.fps.wseq[s][sl],
                                  __ATOMIC_ACQUIRE, __HIP_MEMORY_SCOPE_WORKGROUP);
        } while (!__all(tag == (u32)it));
        // ---- stage 2: 5 parallel conflict-free reads + 4-level u64 DPP
        u32 lo = sm.fps.klo[s][sl], hi = sm.fps.khi[s][sl];
        u32 fx = __builtin_bit_cast(u32, sm.fps.kx[s][sl]);
        u32 fy = __builtin_bit_cast(u32, sm.fps.ky[s][sl]);
        u32 fz = __builtin_bit_cast(u32, sm.fps.kz[s][sl]);
        u64 gk = ((u64)hi << 32) | (u64)lo;
        gk = dpp_max<0xB1>(gk); gk = dpp_max<0x4E>(gk);
        gk = dpp_max<0x141>(gk); gk = dpp_max<0x140>(gk);  // 16-group converge
        u32 n = (u32)__builtin_amdgcn_readfirstlane((int)(~(u32)gk));
        int w = (int)((n >> 6) & 15u);   // winner wave
        ccx = __builtin_bit_cast(float, __builtin_amdgcn_readlane((int)fx, w));
        ccy = __builtin_bit_cast(float, __builtin_amdgcn_readlane((int)fy, w));
        ccz = __builtin_bit_cast(float, __builtin_amdgcn_readlane((int)fz, w));
      }
      if ((it & 7) == 7) __syncthreads();   // ring-slot reuse fence (1/8 iters)
    }
    // ---- bulk dump centers (final barrier was at it=1023)
    for (int i = t; i < 3 * NPOINT; i += 1024){
      int cc = i >> 10, itt = i & 1023;
      out0[((size_t)b*3 + cc)*NPOINT + itt] = sm.fps.cbuf[itt][cc];
    }
    return;
  }

  // -------------------------------------------------------------- conv path
  const int cb = blockIdx.x - 16;
  const int lw = wave & 3, g = wave >> 2;
  const int Wk = cb*4 + g;
  const int lrow = lane & 15, lq = lane >> 4;
  float* bsum0 = statsF;          float* bsqr0 = statsF + 8192;
  float* bsum1 = statsF + 16384;  float* bsqr1 = statsF + 24576;
  float* bsum2 = statsF + 32768;  float* bsqr2 = statsF + 40960;
  float* a0 = statsF + 49152;       float* d0 = a0 + 128;
  float* a1 = statsF + 49152 + 256; float* d1 = a1 + 128;
  float* a2 = statsF + 49152 + 512; float* d2 = a2 + 128;

  // ---- P0: pack XP + weight prep + zero stat buckets
  for (u32 idx = (u32)cb*1024u + t; idx < 16u*16384u; idx += (u32)NCB*1024u){
    u32 b = idx >> 14, n = idx & 16383u;
    const float* xb = xyz + (size_t)b*3*NPTS + n;
    const float* pb = points + (size_t)b*64*NPTS + n;
    u16* dst = XP + ((size_t)b*NPTS + n)*96;
#pragma unroll
    for (int half = 0; half < 2; half++){
      u32 w[24];
#pragma unroll
      for (int q = 0; q < 24; q++){
        int c0 = half*48 + 2*q, c1 = c0 + 1;
        float f0 = (c0 < 3) ? xb[(size_t)c0*NPTS] : (c0 < 67) ? pb[(size_t)(c0-3)*NPTS] : 0.f;
        float f1 = (c1 < 3) ? xb[(size_t)c1*NPTS] : (c1 < 67) ? pb[(size_t)(c1-3)*NPTS] : 0.f;
        w[q] = (u32)f2bf(f0) | ((u32)f2bf(f1) << 16);
      }
#pragma unroll
      for (int q = 0; q < 6; q++){
        uint4 v; v.x = w[4*q]; v.y = w[4*q+1]; v.z = w[4*q+2]; v.w = w[4*q+3];
        *(uint4*)(dst + half*48 + q*8) = v;
      }
    }
  }
  if (cb == 0){
    for (int i = t; i < 64*96; i += 1024){
      int nn = i / 96, kk = i % 96;
      W0bf[i] = (kk < 67) ? f2bf(W0[nn*67 + kk]) : (u16)0;
    }
    for (int i = t; i < 128*64; i += 1024) W1bf[i] = f2bf(W1[i]);
    for (int i = t; i < 128*128; i += 1024) W2bf[i] = f2bf(W2[i]);
  }
  if (cb == 1){
    for (int i = t; i < 49152; i += 1024) statsF[i] = 0.f;
  }
  __threadfence();
  __syncthreads();
  if (t == 0){ arrive(&ctrs[0]); waitc(&ctrs[0], NCB); }
  __syncthreads();

  // ---- P1: layer 0 (gather + K=96 matmul), stats accumulation
  if (t < 128){ sm.conv.lsum[t] = 0.f; sm.conv.lsqr[t] = 0.f; }
  __syncthreads();
  for (int j2 = Wk; j2 < 4096; j2 += NW){
    const int b = j2 >> 8;
    const size_t srow = (size_t)j2 * 128;
    const int gbase = b*32768 + (j2 & 255)*128;
    const int m0 = lw*32 + lrow, m1 = m0 + 16;
    const int p0 = gidx[gbase + m0];
    const int p1 = gidx[gbase + m1];
    const bf16x8* ar0 = (const bf16x8*)(XP + ((size_t)b*NPTS + p0)*96);
    const bf16x8* ar1 = (const bf16x8*)(XP + ((size_t)b*NPTS + p1)*96);
    f32x4 acc[2][4];
#pragma unroll
    for (int mt = 0; mt < 2; mt++)
#pragma unroll
      for (int nt = 0; nt < 4; nt++){ f32x4 z = {0.f,0.f,0.f,0.f}; acc[mt][nt] = z; }
#pragma unroll
    for (int ks = 0; ks < 3; ks++){
      bf16x8 af0 = ar0[ks*4 + lq];
      bf16x8 af1 = ar1[ks*4 + lq];
#pragma unroll
      for (int nt = 0; nt < 4; nt++){
        bf16x8 bb = *(const bf16x8*)(W0bf + (nt*16 + lrow)*96 + ks*32 + lq*8);
        acc[0][nt] = __builtin_amdgcn_mfma_f32_16x16x32_bf16(af0, bb, acc[0][nt], 0, 0, 0);
        acc[1][nt] = __builtin_amdgcn_mfma_f32_16x16x32_bf16(af1, bb, acc[1][nt], 0, 0, 0);
      }
    }
#pragma unroll
    for (int nt = 0; nt < 4; nt++){
      float s = 0.f, s2 = 0.f;
#pragma unroll
      for (int mt = 0; mt < 2; mt++){
#pragma unroll
        for (int i = 0; i < 4; i++){
          float u = acc[mt][nt][i];
          s += u; s2 = fmaf(u, u, s2);
          int m = lw*32 + mt*16 + lq*4 + i;
          y0[(srow + m)*64 + nt*16 + lrow] = f2bf(u);
        }
      }
      s  += __shfl_xor(s, 16, 64);  s  += __shfl_xor(s, 32, 64);
      s2 += __shfl_xor(s2, 16, 64); s2 += __shfl_xor(s2, 32, 64);
      if (lane < 16){ atomicAdd(&sm.conv.lsum[nt*16 + lane], s); atomicAdd(&sm.conv.lsqr[nt*16 + lane], s2); }
    }
  }
  __syncthreads();
  if (t < 64){
    atomicAdd(&bsum0[(cb & 63)*128 + t], sm.conv.lsum[t]);
    atomicAdd(&bsqr0[(cb & 63)*128 + t], sm.conv.lsqr[t]);
  }
  __threadfence();
  __syncthreads();
  if (t == 0) arrive(&ctrs[1]);
  if (cb == 0){
    if (t == 0) waitc(&ctrs[1], NCB);
    __syncthreads();
    if (t < 64){
      float s = 0.f, s2 = 0.f;
      for (int k = 0; k < 64; k++){ s += bsum0[k*128 + t]; s2 += bsqr0[k*128 + t]; }
      const float inv = 1.f / (float)STOT;
      float m = s * inv, v = s2 * inv - m*m;
      float aa = g0v[t] / sqrtf(v + 1e-5f);
      a0[t] = aa; d0[t] = be0[t] - m*aa;
    }
    __threadfence();
    __syncthreads();
    if (t == 0) arrive(&ctrs[2]);
  }
  if (t == 0) waitc(&ctrs[2], 1);
  __syncthreads();

  // ---- P2: layer 1 (K=64 -> 128)
  if (t < 128){ sm.conv.lsum[t] = 0.f; sm.conv.lsqr[t] = 0.f; }
  if (t < 64){ sm.conv.av[t] = a0[t]; sm.conv.dv[t] = d0[t]; }
  __syncthreads();
  for (int j2 = Wk; j2 < 4096; j2 += NW){
    const size_t srow = (size_t)j2 * 128;
    const int m0 = lw*32 + lrow, m1 = m0 + 16;
    const u16* row0 = y0 + (srow + m0)*64;
    const u16* row1 = y0 + (srow + m1)*64;
    f32x4 acc[2][8];
#pragma unroll
    for (int mt = 0; mt < 2; mt++)
#pragma unroll
      for (int nt = 0; nt < 8; nt++){ f32x4 z = {0.f,0.f,0.f,0.f}; acc[mt][nt] = z; }
#pragma unroll
    for (int ks = 0; ks < 2; ks++){
      const int ko = ks*32 + lq*8;
      bf16x8 af0 = load_bn_relu(row0, ko, sm.conv.av, sm.conv.dv);
      bf16x8 af1 = load_bn_relu(row1, ko, sm.conv.av, sm.conv.dv);
#pragma unroll
      for (int nt = 0; nt < 8; nt++){
        bf16x8 bb = *(const bf16x8*)(W1bf + (nt*16 + lrow)*64 + ko);
        acc[0][nt] = __builtin_amdgcn_mfma_f32_16x16x32_bf16(af0, bb, acc[0][nt], 0, 0, 0);
        acc[1][nt] = __builtin_amdgcn_mfma_f32_16x16x32_bf16(af1, bb, acc[1][nt], 0, 0, 0);
      }
    }
#pragma unroll
    for (int nt = 0; nt < 8; nt++){
      float s = 0.f, s2 = 0.f;
#pragma unroll
      for (int mt = 0; mt < 2; mt++){
#pragma unroll
        for (int i = 0; i < 4; i++){
          float u = acc[mt][nt][i];
          s += u; s2 = fmaf(u, u, s2);
          int m = lw*32 + mt*16 + lq*4 + i;
          y1[(srow + m)*128 + nt*16 + lrow] = f2bf(u);
        }
      }
      s  += __shfl_xor(s, 16, 64);  s  += __shfl_xor(s, 32, 64);
      s2 += __shfl_xor(s2, 16, 64); s2 += __shfl_xor(s2, 32, 64);
      if (lane < 16){ atomicAdd(&sm.conv.lsum[nt*16 + lane], s); atomicAdd(&sm.conv.lsqr[nt*16 + lane], s2); }
    }
  }
  __syncthreads();
  if (t < 128){
    atomicAdd(&bsum1[(cb & 63)*128 + t], sm.conv.lsum[t]);
    atomicAdd(&bsqr1[(cb & 63)*128 + t], sm.conv.lsqr[t]);
  }
  __threadfence();
  __syncthreads();
  if (t == 0) arrive(&ctrs[3]);
  if (cb == 0){
    if (t == 0) waitc(&ctrs[3], NCB);
    __syncthreads();
    if (t < 128){
      float s = 0.f, s2 = 0.f;
      for (int k = 0; k < 64; k++){ s += bsum1[k*128 + t]; s2 += bsqr1[k*128 + t]; }
      const float inv = 1.f / (float)STOT;
      float m = s * inv, v = s2 * inv - m*m;
      float aa = g1v[t] / sqrtf(v + 1e-5f);
      a1[t] = aa; d1[t] = be1[t] - m*aa;
    }
    __threadfence();
    __syncthreads();
    if (t == 0) arrive(&ctrs[4]);
  }
  if (t == 0) waitc(&ctrs[4], 1);
  __syncthreads();

  // ---- P3: layer 2 (K=128 -> 128) + per-group max/min of pre-BN y2
  if (t < 128){ sm.conv.lsum[t] = 0.f; sm.conv.lsqr[t] = 0.f;
                sm.conv.av[t] = a1[t]; sm.conv.dv[t] = d1[t]; }
  __syncthreads();
  for (int j2 = Wk; j2 < 4096; j2 += NW){
    const size_t srow = (size_t)j2 * 128;
    const int m0 = lw*32 + lrow, m1 = m0 + 16;
    const u16* row0 = y1 + (srow + m0)*128;
    const u16* row1 = y1 + (srow + m1)*128;
    f32x4 acc[2][8];
#pragma unroll
    for (int mt = 0; mt < 2; mt++)
#pragma unroll
      for (int nt = 0; nt < 8; nt++){ f32x4 z = {0.f,0.f,0.f,0.f}; acc[mt][nt] = z; }
#pragma unroll
    for (int ks = 0; ks < 4; ks++){
      const int ko = ks*32 + lq*8;
      bf16x8 af0 = load_bn_relu(row0, ko, sm.conv.av, sm.conv.dv);
      bf16x8 af1 = load_bn_relu(row1, ko, sm.conv.av, sm.conv.dv);
#pragma unroll
      for (int nt = 0; nt < 8; nt++){
        bf16x8 bb = *(const bf16x8*)(W2bf + (nt*16 + lrow)*128 + ko);
        acc[0][nt] = __builtin_amdgcn_mfma_f32_16x16x32_bf16(af0, bb, acc[0][nt], 0, 0, 0);
        acc[1][nt] = __builtin_amdgcn_mfma_f32_16x16x32_bf16(af1, bb, acc[1][nt], 0, 0, 0);
      }
    }
#pragma unroll
    for (int nt = 0; nt < 8; nt++){
      float s = 0.f, s2 = 0.f, mx = -3.4e38f, mn = 3.4e38f;
#pragma unroll
      for (int mt = 0; mt < 2; mt++){
#pragma unroll
        for (int i = 0; i < 4; i++){
          float u = acc[mt][nt][i];
          s += u; s2 = fmaf(u, u, s2);
          mx = fmaxf(mx, u); mn = fminf(mn, u);
        }
      }
      s  += __shfl_xor(s, 16, 64);  s  += __shfl_xor(s, 32, 64);
      s2 += __shfl_xor(s2, 16, 64); s2 += __shfl_xor(s2, 32, 64);
      mx = fmaxf(mx, __shfl_xor(mx, 16, 64)); mx = fmaxf(mx, __shfl_xor(mx, 32, 64));
      mn = fminf(mn, __shfl_xor(mn, 16, 64)); mn = fminf(mn, __shfl_xor(mn, 32, 64));
      if (lane < 16){
        size_t gi = ((size_t)j2*4 + lw)*128 + nt*16 + lane;
        maxb[gi] = mx; minb[gi] = mn;
        atomicAdd(&sm.conv.lsum[nt*16 + lane], s); atomicAdd(&sm.conv.lsqr[nt*16 + lane], s2);
      }
    }
  }
  __syncthreads();
  if (t < 128){
    atomicAdd(&bsum2[(cb & 63)*128 + t], sm.conv.lsum[t]);
    atomicAdd(&bsqr2[(cb & 63)*128 + t], sm.conv.lsqr[t]);
  }
  __threadfence();
  __syncthreads();
  if (t == 0) arrive(&ctrs[5]);
  if (cb == 0){
    if (t == 0) waitc(&ctrs[5], NCB);
    __syncthreads();
    if (t < 128){
      float s = 0.f, s2 = 0.f;
      for (int k = 0; k < 64; k++){ s += bsum2[k*128 + t]; s2 += bsqr2[k*128 + t]; }
      const float inv = 1.f / (float)STOT;
      float m = s * inv, v = s2 * inv - m*m;
      float aa = g2v[t] / sqrtf(v + 1e-5f);
      a2[t] = aa; d2[t] = be2[t] - m*aa;
    }
    __threadfence();
    __syncthreads();
    if (t == 0) arrive(&ctrs[6]);
  }
  if (t == 0) waitc(&ctrs[6], 1);
  __syncthreads();

  // ---- P4: final BN2+relu on group max/min, store [B,128,NP] (np coalesced)
  for (u32 e = (u32)cb*1024u + t; e < 16u*1024u*128u; e += (u32)NCB*1024u){
    u32 np = e & 1023u;
    u32 c  = (e >> 10) & 127u;
    u32 b  = e >> 17;
    size_t gi = ((size_t)b*1024 + np)*128 + c;
    float a = a2[c];
    float v = (a >= 0.f) ? maxb[gi] : minb[gi];
    out1[((size_t)b*128 + c)*1024 + np] = fmaxf(fmaf(a, v, d2[c]), 0.f);
  }
}

// ---------------------------------------------------------------- launch
extern "C" void kernel_launch(void* const* d_in, const int* in_sizes, int n_in,
                              void* d_out, int out_size, void* d_ws, size_t ws_size,
                              hipStream_t stream) {
  const float* xyz    = (const float*)d_in[0];
  const float* points = (const float*)d_in[1];
  const int*   finit  = (const int*)d_in[2];
  const int*   gidx   = (const int*)d_in[3];
  const float* W0  = (const float*)d_in[4];
  const float* g0v = (const float*)d_in[6];
  const float* be0 = (const float*)d_in[7];
  const float* W1  = (const float*)d_in[8];
  const float* g1v = (const float*)d_in[10];
  const float* be1 = (const float*)d_in[11];
  const float* W2  = (const float*)d_in[12];
  const float* g2v = (const float*)d_in[14];
  const float* be2 = (const float*)d_in[15];

  float* out0 = (float*)d_out;
  float* out1 = out0 + 16*3*NPOINT;   // 49152

  char* ws = (char*)d_ws;
  // layout (bytes):
  //   [0, 128M)            y1 (l1 out); XP aliases [0,48M) (dead before l1 writes)
  //   [128M, 192M)         y0 (l0 out); maxb/minb alias (y0 dead after l1)
  //   [192M, ...)          statsF, W*bf, ctrs
  u16* y1 = (u16*)ws;
  u16* XP = (u16*)ws;
  u16* y0 = (u16*)(ws + 134217728);
  float* maxb = (float*)(ws + 134217728);
  float* minb = (float*)(ws + 134217728 + 8388608);
  float* statsF = (float*)(ws + 201326592);
  u16* W0bf = (u16*)(ws + 201326592 + 49920*4);          // 201526272
  u16* W1bf = W0bf + 64*96;
  u16* W2bf = W1bf + 128*64;
  u32* ctrs = (u32*)(ws + 205782016);                    // 64 u32

  zero_kernel<<<1, 64, 0, stream>>>(ctrs);
  mega_kernel<<<256, 1024, 0, stream>>>(
      xyz, points, finit, gidx,
      W0, g0v, be0, W1, g1v, be1, W2, g2v, be2,
      out0, out1, XP, y0, y1, maxb, minb, statsF,
      W0bf, W1bf, W2bf, ctrs);
}

// Round 9
// 2047.110 us; speedup vs baseline: 1.1709x; 1.1709x over previous
//
#include <hip/hip_runtime.h>

typedef short bf16x8 __attribute__((ext_vector_type(8)));
typedef float f32x4 __attribute__((ext_vector_type(4)));
typedef unsigned short u16;
typedef unsigned int u32;
typedef unsigned long long u64;

#define NPTS 16384
#define NPOINT 1024
#define STOT 524288   // 16*1024*32 samples
#define NCB 240       // conv blocks (blocks 16..255)
#define NW  960       // conv workers (4-wave groups)

__device__ __forceinline__ u16 f2bf(float f){
  u32 u = __builtin_bit_cast(u32, f);
  u += 0x7fffu + ((u >> 16) & 1u);
  return (u16)(u >> 16);
}
__device__ __forceinline__ float bf2f(u16 u){
  u32 x = ((u32)u) << 16;
  return __builtin_bit_cast(float, x);
}

// f32 max/min-combine across lanes via DPP.
template<int CTRL>
__device__ __forceinline__ float dpp_maxf(float v){
  int x = __builtin_amdgcn_update_dpp(0, __builtin_bit_cast(int, v), CTRL, 0xf, 0xf, true);
  return fmaxf(v, __builtin_bit_cast(float, x));
}
template<int CTRL>
__device__ __forceinline__ float dpp_minf(float v){
  int x = __builtin_amdgcn_update_dpp(0, __builtin_bit_cast(int, v), CTRL, 0xf, 0xf, true);
  return fminf(v, __builtin_bit_cast(float, x));
}
// full-wave reduce -> uniform scalar (value from lane 63)
__device__ __forceinline__ float wave_maxf(float v){
  v = dpp_maxf<0xB1>(v); v = dpp_maxf<0x4E>(v); v = dpp_maxf<0x141>(v);
  v = dpp_maxf<0x140>(v); v = dpp_maxf<0x142>(v); v = dpp_maxf<0x143>(v);
  return __builtin_bit_cast(float, __builtin_amdgcn_readlane(__builtin_bit_cast(int, v), 63));
}
__device__ __forceinline__ float wave_minf(float v){
  v = dpp_minf<0xB1>(v); v = dpp_minf<0x4E>(v); v = dpp_minf<0x141>(v);
  v = dpp_minf<0x140>(v); v = dpp_minf<0x142>(v); v = dpp_minf<0x143>(v);
  return __builtin_bit_cast(float, __builtin_amdgcn_readlane(__builtin_bit_cast(int, v), 63));
}
// 64-bit max-combine across lanes via DPP (exact keys).
template<int CTRL>
__device__ __forceinline__ u64 dpp_max(u64 key){
  u32 lo = (u32)key, hi = (u32)(key >> 32);
  u32 lo1 = (u32)__builtin_amdgcn_update_dpp(0, (int)lo, CTRL, 0xf, 0xf, true);
  u32 hi1 = (u32)__builtin_amdgcn_update_dpp(0, (int)hi, CTRL, 0xf, 0xf, true);
  u64 k1 = ((u64)hi1 << 32) | (u64)lo1;
  return (k1 > key) ? k1 : key;
}

__device__ __forceinline__ void arrive(u32* c){
  __hip_atomic_fetch_add(c, 1u, __ATOMIC_RELEASE, __HIP_MEMORY_SCOPE_AGENT);
}
__device__ __forceinline__ void waitc(u32* c, u32 tgt){
  while (__hip_atomic_load(c, __ATOMIC_ACQUIRE, __HIP_MEMORY_SCOPE_AGENT) < tgt)
    __builtin_amdgcn_s_sleep(16);
}

// FPS LDS: srt = one-time Morton counting-sort scratch; run = iter-loop state.
// THE UNION ALIASES: run.* overlaps srt.sidx — every srt read must complete
// (barrier) before ANY run write (r8 post-mortem: missing barrier let t0's
// csl write corrupt sidx -> 4GB OOB gather -> GPU fault -> container death).
// r4 lesson: small-stride key arrays only. r6 lesson: per-point coords in REGS.
struct FpsRun {
  float cbuf[NPOINT][3];     // centers, bulk-dumped post-loop (no VM ops in loop)
  uint2 wkey[2][16];         // (x=~oidx, y=ms bits) per wave, parity ping-pong
  u32   wroute[2][16];       // (lane<<4)|k of the wave-winner holder
  float4 csl[2];             // current center, parity ping-pong (r0-proven)
};
struct FpsSrt {
  u32 hist[256];             // Morton-bin counters (histogram, then scatter ctr)
  float red[16][6];          // per-wave min/max for block AABB
  u32 sidx[16384];           // orig index, grouped by Morton bin
};
struct FpsS  { union { FpsRun run; FpsSrt srt; } u; };
struct ConvS { float lsum[128]; float lsqr[128]; float av[128]; float dv[128]; };
union SMemU  { FpsS fps; ConvS conv; };

__device__ __forceinline__ bf16x8 load_bn_relu(const u16* __restrict__ row, int ko,
                                               const float* __restrict__ av,
                                               const float* __restrict__ dv){
  uint4 r = *(const uint4*)(row + ko);
  u32 w[4] = {r.x, r.y, r.z, r.w};
  bf16x8 out;
#pragma unroll
  for (int jj = 0; jj < 8; jj++){
    u16 us = (u16)(w[jj >> 1] >> ((jj & 1) * 16));
    float h = fmaxf(fmaf(av[ko + jj], bf2f(us), dv[ko + jj]), 0.f);
    out[jj] = (short)f2bf(h);
  }
  return out;
}

// zero the sync counters (ws is re-poisoned 0xAA before every call)
__global__ void zero_kernel(u32* __restrict__ ctrs){
  if (threadIdx.x < 64) ctrs[threadIdx.x] = 0;
}

// ================================================================ MEGA KERNEL
// blocks 0..15  : FPS with EXACT wave-level pruning. One-time: Morton-bin
//                 counting sort -> each wave owns 1024 spatially-compact points
//                 (coords in regs, per-lane points ASC by orig idx via Batcher
//                 net -> in-lane first-k tie == smallest orig idx). Per iter:
//                 wave skips its whole distance pass iff d^2(c, waveAABB)*
//                 0.99999 >= bv_wave (conservative, bit-exact no-op proof);
//                 skipped waves republish cached (ms,~oidx,route). Selection
//                 keys carry ORIGINAL indices -> reference argmax semantics.
//                 r0's proven 2-barrier LDS csl broadcast retained.
// blocks 16..255: persistent conv chain (unchanged).
// Cross-block per-iter sync banned (r1). Center broadcast on-chip only (r2).
__global__ __launch_bounds__(1024, 4) void mega_kernel(
    const float* __restrict__ xyz, const float* __restrict__ points,
    const int* __restrict__ finit, const int* __restrict__ gidx,
    const float* __restrict__ W0, const float* __restrict__ g0v, const float* __restrict__ be0,
    const float* __restrict__ W1, const float* __restrict__ g1v, const float* __restrict__ be1,
    const float* __restrict__ W2, const float* __restrict__ g2v, const float* __restrict__ be2,
    float* __restrict__ out0, float* __restrict__ out1,
    u16* __restrict__ XP, u16* __restrict__ y0, u16* __restrict__ y1,
    float* __restrict__ maxb, float* __restrict__ minb,
    float* __restrict__ statsF,
    u16* __restrict__ W0bf, u16* __restrict__ W1bf, u16* __restrict__ W2bf,
    u32* __restrict__ ctrs){
  __shared__ SMemU sm;
  const int t = threadIdx.x;
  const int wave = t >> 6, lane = t & 63;

  if (blockIdx.x < 16){
    // ------------------------------------------------------------ FPS path
    const int b = blockIdx.x;
    const float* xb = xyz + (size_t)b * 3 * NPTS;
    float px[16], py[16], pz[16], dist[16];
    u32 opk[8];

    // ---- Phase A: linear load + block AABB (for Morton quantization)
    float mnx = 1e30f, mxx = -1e30f, mny = 1e30f, mxy = -1e30f, mnz = 1e30f, mxz = -1e30f;
#pragma unroll
    for (int k = 0; k < 16; k++){
      int n = (k << 10) + t;
      float x = xb[n], y = xb[NPTS + n], z = xb[2*NPTS + n];
      px[k] = x; py[k] = y; pz[k] = z;
      mnx = fminf(mnx, x); mxx = fmaxf(mxx, x);
      mny = fminf(mny, y); mxy = fmaxf(mxy, y);
      mnz = fminf(mnz, z); mxz = fmaxf(mxz, z);
    }
    mnx = wave_minf(mnx); mxx = wave_maxf(mxx);
    mny = wave_minf(mny); mxy = wave_maxf(mxy);
    mnz = wave_minf(mnz); mxz = wave_maxf(mxz);
    if (lane == 0){
      sm.fps.u.srt.red[wave][0] = mnx; sm.fps.u.srt.red[wave][1] = mxx;
      sm.fps.u.srt.red[wave][2] = mny; sm.fps.u.srt.red[wave][3] = mxy;
      sm.fps.u.srt.red[wave][4] = mnz; sm.fps.u.srt.red[wave][5] = mxz;
    }
    for (int i = t; i < 256; i += 1024) sm.fps.u.srt.hist[i] = 0;
    __syncthreads();
#pragma unroll
    for (int w = 0; w < 16; w++){
      mnx = fminf(mnx, sm.fps.u.srt.red[w][0]); mxx = fmaxf(mxx, sm.fps.u.srt.red[w][1]);
      mny = fminf(mny, sm.fps.u.srt.red[w][2]); mxy = fmaxf(mxy, sm.fps.u.srt.red[w][3]);
      mnz = fminf(mnz, sm.fps.u.srt.red[w][4]); mxz = fmaxf(mxz, sm.fps.u.srt.red[w][5]);
    }
    const float sclx = 7.9999f / fmaxf(mxx - mnx, 1e-20f);
    const float scly = 7.9999f / fmaxf(mxy - mny, 1e-20f);
    const float sclz = 3.9999f / fmaxf(mxz - mnz, 1e-20f);

    // ---- Phase B: Morton keys (3,3,2 bits) + histogram
    u32 kq[16];
#pragma unroll
    for (int k = 0; k < 16; k++){
      int xq = (int)((px[k] - mnx) * sclx); xq = min(max(xq, 0), 7);
      int yq = (int)((py[k] - mny) * scly); yq = min(max(yq, 0), 7);
      int zq = (int)((pz[k] - mnz) * sclz); zq = min(max(zq, 0), 3);
      u32 key = ((u32)(xq >> 2) << 7) | ((u32)(yq >> 2) << 6) |
                ((u32)((xq >> 1) & 1) << 5) | ((u32)((yq >> 1) & 1) << 4) |
                ((u32)((zq >> 1) & 1) << 3) |
                ((u32)(xq & 1) << 2) | ((u32)(yq & 1) << 1) | (u32)(zq & 1);
      kq[k] = key;
      atomicAdd(&sm.fps.u.srt.hist[key], 1u);
    }
    __syncthreads();
    // ---- Phase C: exclusive scan (t==0, one-time) + scatter of orig indices
    if (t == 0){
      u32 run2 = 0;
      for (int i = 0; i < 256; i++){ u32 c = sm.fps.u.srt.hist[i]; sm.fps.u.srt.hist[i] = run2; run2 += c; }
    }
    __syncthreads();
#pragma unroll
    for (int k = 0; k < 16; k++){
      u32 pos = atomicAdd(&sm.fps.u.srt.hist[kq[k]], 1u);
      sm.fps.u.srt.sidx[pos] = (u32)((k << 10) + t);
    }
    __syncthreads();
    // ---- Phase D: gather wave-contiguous chunk (defensive mask: a corrupted
    // index must fail via absmax, not fault the GPU)
    u32 o[16];
#pragma unroll
    for (int k = 0; k < 16; k++)
      o[k] = sm.fps.u.srt.sidx[(wave << 10) + (k << 6) + lane] & 16383u;
    __syncthreads();   // ALL sidx reads complete before ANY run-union write (r8 crash fix)
    // per-lane sort by orig idx: Batcher odd-even mergesort, n=16, ascending
#pragma unroll
    for (int P = 1; P < 16; P <<= 1){
#pragma unroll
      for (int K = P; K >= 1; K >>= 1){
#pragma unroll
        for (int J = K & (P - 1); J + K < 16; J += 2*K){
#pragma unroll
          for (int I = 0; I < K; I++){
            if ((I + J + K < 16) && ((I + J) / (2*P) == (I + J + K) / (2*P))){
              u32 a = o[I + J], c2 = o[I + J + K];
              o[I + J] = min(a, c2); o[I + J + K] = max(a, c2);
            }
          }
        }
      }
    }
#pragma unroll
    for (int j = 0; j < 8; j++) opk[j] = o[2*j] | (o[2*j + 1] << 16);
    float wlx = 1e30f, whx = -1e30f, wly = 1e30f, why = -1e30f, wlz = 1e30f, whz = -1e30f;
#pragma unroll
    for (int k = 0; k < 16; k++){
      float x = xb[o[k]], y = xb[NPTS + o[k]], z = xb[2*NPTS + o[k]];
      px[k] = x; py[k] = y; pz[k] = z; dist[k] = 1e10f;
      wlx = fminf(wlx, x); whx = fmaxf(whx, x);
      wly = fminf(wly, y); why = fmaxf(why, y);
      wlz = fminf(wlz, z); whz = fmaxf(whz, z);
    }
    const float lox = wave_minf(wlx), hix = wave_maxf(whx);
    const float loy = wave_minf(wly), hiy = wave_maxf(why);
    const float loz = wave_minf(wlz), hiz = wave_maxf(whz);
    // initial center (one-time global loads; exact input bits). Writing run.csl
    // is safe here: the sidx-read barrier above has retired all srt reads.
    const int far0 = finit[b];
    if (t == 0){
      sm.fps.u.run.csl[0] = make_float4(xb[far0], xb[NPTS + far0], xb[2*NPTS + far0], 0.f);
    }
    float bvw = 1e10f;
    uint2 cck = make_uint2(0u, 0u); u32 ccrt = 0u;
    __syncthreads();

    // ---- iteration loop (r0 2-barrier skeleton + wave prune)
    for (int it = 0; it < NPOINT; it++){
      const int p = it & 1;
      float4 cc = sm.fps.u.run.csl[p];
      if (t == 0){
        sm.fps.u.run.cbuf[it][0] = cc.x;
        sm.fps.u.run.cbuf[it][1] = cc.y;
        sm.fps.u.run.cbuf[it][2] = cc.z;
      }
      // wave-uniform prune test: d^2(c, AABB), conservatively deflated
      float dlx = fmaxf(fmaxf(lox - cc.x, cc.x - hix), 0.f);
      float dly = fmaxf(fmaxf(loy - cc.y, cc.y - hiy), 0.f);
      float dlz = fmaxf(fmaxf(loz - cc.z, cc.z - hiz), 0.f);
      float d2 = dlx*dlx + dly*dly + dlz*dlz;
      bool prune = (d2 * 0.99999f >= bvw);
      uint2 outkey; u32 outrt;
      if (!prune){
        float bv = -1.f; int bk = 0;
        {
#pragma clang fp contract(off)
#pragma unroll
          for (int k = 0; k < 16; k++){
            float dx = px[k] - cc.x;
            float dy = py[k] - cc.y;
            float dz = pz[k] - cc.z;
            float dd = dx*dx + dy*dy + dz*dz;   // matches reference eval order
            float dm = fminf(dist[k], dd);
            dist[k] = dm;
            bool g = dm > bv;
            bv = g ? dm : bv;  bk = g ? k : bk;
          }
        }
        // stage 1: wave argmax, keys on ORIGINAL indices
        float ms = wave_maxf(bv);
        u64 mk = __ballot(bv == ms);
        int L, kwin; u32 oidx;
        if (__popcll(mk) == 1){
          L = (int)__builtin_ctzll(mk);
          kwin = __builtin_amdgcn_readlane(bk, L);
          u32 s0 = (u32)__builtin_amdgcn_readlane((int)opk[0], L);
          u32 s1 = (u32)__builtin_amdgcn_readlane((int)opk[1], L);
          u32 s2 = (u32)__builtin_amdgcn_readlane((int)opk[2], L);
          u32 s3 = (u32)__builtin_amdgcn_readlane((int)opk[3], L);
          u32 s4 = (u32)__builtin_amdgcn_readlane((int)opk[4], L);
          u32 s5 = (u32)__builtin_amdgcn_readlane((int)opk[5], L);
          u32 s6 = (u32)__builtin_amdgcn_readlane((int)opk[6], L);
          u32 s7 = (u32)__builtin_amdgcn_readlane((int)opk[7], L);
          int kh = kwin >> 1;
          u32 osel = s0;
          osel = (kh == 1) ? s1 : osel; osel = (kh == 2) ? s2 : osel;
          osel = (kh == 3) ? s3 : osel; osel = (kh == 4) ? s4 : osel;
          osel = (kh == 5) ? s5 : osel; osel = (kh == 6) ? s6 : osel;
          osel = (kh == 7) ? s7 : osel;
          oidx = (osel >> ((kwin & 1) << 4)) & 0xFFFFu;
        } else {
          // exact-tie: u64 (dist, ~oidx) DPP chain (static-indexed opk select)
          int bh = bk >> 1;
          u32 po = opk[0];
          po = (bh == 1) ? opk[1] : po; po = (bh == 2) ? opk[2] : po;
          po = (bh == 3) ? opk[3] : po; po = (bh == 4) ? opk[4] : po;
          po = (bh == 5) ? opk[5] : po; po = (bh == 6) ? opk[6] : po;
          po = (bh == 7) ? opk[7] : po;
          u32 myo = (po >> ((bk & 1) << 4)) & 0xFFFFu;
          u64 mykey = ((u64)__builtin_bit_cast(u32, bv) << 32) | (u64)(~myo);
          u64 kr = mykey;
          kr = dpp_max<0xB1>(kr); kr = dpp_max<0x4E>(kr);
          kr = dpp_max<0x141>(kr); kr = dpp_max<0x140>(kr);
          kr = dpp_max<0x142>(kr); kr = dpp_max<0x143>(kr);
          u32 wlo = (u32)__builtin_amdgcn_readlane((int)(u32)kr, 63);
          u32 whi = (u32)__builtin_amdgcn_readlane((int)(u32)(kr >> 32), 63);
          u64 win = ((u64)whi << 32) | (u64)wlo;
          L = (int)__builtin_ctzll(__ballot(mykey == win));
          kwin = __builtin_amdgcn_readlane(bk, L);
          oidx = (~wlo) & 0xFFFFu;
        }
        outkey.x = ~oidx; outkey.y = __builtin_bit_cast(u32, ms);
        outrt = ((u32)L << 4) | (u32)kwin;
        bvw = ms; cck = outkey; ccrt = outrt;
      } else {
        outkey = cck; outrt = ccrt;
      }
      if (lane == 0){
        sm.fps.u.run.wkey[p][wave] = outkey;
        sm.fps.u.run.wroute[p][wave] = outrt;
      }
      __syncthreads();                 // B1
      // ---- stage 2: reduce 16 wave keys -> winner wave + route
      uint2 wk = sm.fps.u.run.wkey[p][lane & 15];
      u32 rta = sm.fps.u.run.wroute[p][lane & 15];
      float wv = __builtin_bit_cast(float, wk.y);
      float g4 = wv;
      g4 = dpp_maxf<0xB1>(g4); g4 = dpp_maxf<0x4E>(g4);
      g4 = dpp_maxf<0x141>(g4); g4 = dpp_maxf<0x140>(g4);
      float gms = __builtin_bit_cast(float, __builtin_amdgcn_readfirstlane(__builtin_bit_cast(int, g4)));
      u64 mk2 = __ballot(wv == gms);
      u32 lo16 = (u32)mk2 & 0xFFFFu;
      int wstar;
      if (__popc(lo16) == 1){
        wstar = (int)__builtin_ctz(lo16);
      } else {
        u64 mykey2 = ((u64)wk.y << 32) | (u64)wk.x;
        u64 kr = mykey2;
        kr = dpp_max<0xB1>(kr); kr = dpp_max<0x4E>(kr);
        kr = dpp_max<0x141>(kr); kr = dpp_max<0x140>(kr);
        u32 wlo = (u32)__builtin_amdgcn_readfirstlane((int)(u32)kr);
        u32 whi = (u32)__builtin_amdgcn_readfirstlane((int)(u32)(kr >> 32));
        u64 win = ((u64)whi << 32) | (u64)wlo;
        wstar = (int)__builtin_ctz((u32)__ballot(mykey2 == win) & 0xFFFFu);
      }
      u32 rt = (u32)__builtin_amdgcn_readlane((int)rta, wstar);
      if (wave == wstar && lane == (int)(rt >> 4)){
        int kk = (int)(rt & 15u);
        float sx = px[0], sy = py[0], sz = pz[0];
#pragma unroll
        for (int k = 1; k < 16; k++){
          bool e = (kk == k);
          sx = e ? px[k] : sx; sy = e ? py[k] : sy; sz = e ? pz[k] : sz;
        }
        sm.fps.u.run.csl[p ^ 1] = make_float4(sx, sy, sz, 0.f);
      }
      __syncthreads();                 // B2
    }
    // ---- bulk dump centers
    for (int i = t; i < 3 * NPOINT; i += 1024){
      int cc2 = i >> 10, itt = i & 1023;
      out0[((size_t)b*3 + cc2)*NPOINT + itt] = sm.fps.u.run.cbuf[itt][cc2];
    }
    return;
  }

  // -------------------------------------------------------------- conv path
  const int cb = blockIdx.x - 16;
  const int lw = wave & 3, g = wave >> 2;
  const int Wk = cb*4 + g;
  const int lrow = lane & 15, lq = lane >> 4;
  float* bsum0 = statsF;          float* bsqr0 = statsF + 8192;
  float* bsum1 = statsF + 16384;  float* bsqr1 = statsF + 24576;
  float* bsum2 = statsF + 32768;  float* bsqr2 = statsF + 40960;
  float* a0 = statsF + 49152;       float* d0 = a0 + 128;
  float* a1 = statsF + 49152 + 256; float* d1 = a1 + 128;
  float* a2 = statsF + 49152 + 512; float* d2 = a2 + 128;

  // ---- P0: pack XP + weight prep + zero stat buckets
  for (u32 idx = (u32)cb*1024u + t; idx < 16u*16384u; idx += (u32)NCB*1024u){
    u32 b = idx >> 14, n = idx & 16383u;
    const float* xb = xyz + (size_t)b*3*NPTS + n;
    const float* pb = points + (size_t)b*64*NPTS + n;
    u16* dst = XP + ((size_t)b*NPTS + n)*96;
#pragma unroll
    for (int half = 0; half < 2; half++){
      u32 w[24];
#pragma unroll
      for (int q = 0; q < 24; q++){
        int c0 = half*48 + 2*q, c1 = c0 + 1;
        float f0 = (c0 < 3) ? xb[(size_t)c0*NPTS] : (c0 < 67) ? pb[(size_t)(c0-3)*NPTS] : 0.f;
        float f1 = (c1 < 3) ? xb[(size_t)c1*NPTS] : (c1 < 67) ? pb[(size_t)(c1-3)*NPTS] : 0.f;
        w[q] = (u32)f2bf(f0) | ((u32)f2bf(f1) << 16);
      }
#pragma unroll
      for (int q = 0; q < 6; q++){
        uint4 v; v.x = w[4*q]; v.y = w[4*q+1]; v.z = w[4*q+2]; v.w = w[4*q+3];
        *(uint4*)(dst + half*48 + q*8) = v;
      }
    }
  }
  if (cb == 0){
    for (int i = t; i < 64*96; i += 1024){
      int nn = i / 96, kk = i % 96;
      W0bf[i] = (kk < 67) ? f2bf(W0[nn*67 + kk]) : (u16)0;
    }
    for (int i = t; i < 128*64; i += 1024) W1bf[i] = f2bf(W1[i]);
    for (int i = t; i < 128*128; i += 1024) W2bf[i] = f2bf(W2[i]);
  }
  if (cb == 1){
    for (int i = t; i < 49152; i += 1024) statsF[i] = 0.f;
  }
  __threadfence();
  __syncthreads();
  if (t == 0){ arrive(&ctrs[0]); waitc(&ctrs[0], NCB); }
  __syncthreads();

  // ---- P1: layer 0 (gather + K=96 matmul), stats accumulation
  if (t < 128){ sm.conv.lsum[t] = 0.f; sm.conv.lsqr[t] = 0.f; }
  __syncthreads();
  for (int j2 = Wk; j2 < 4096; j2 += NW){
    const int b = j2 >> 8;
    const size_t srow = (size_t)j2 * 128;
    const int gbase = b*32768 + (j2 & 255)*128;
    const int m0 = lw*32 + lrow, m1 = m0 + 16;
    const int p0 = gidx[gbase + m0];
    const int p1 = gidx[gbase + m1];
    const bf16x8* ar0 = (const bf16x8*)(XP + ((size_t)b*NPTS + p0)*96);
    const bf16x8* ar1 = (const bf16x8*)(XP + ((size_t)b*NPTS + p1)*96);
    f32x4 acc[2][4];
#pragma unroll
    for (int mt = 0; mt < 2; mt++)
#pragma unroll
      for (int nt = 0; nt < 4; nt++){ f32x4 z = {0.f,0.f,0.f,0.f}; acc[mt][nt] = z; }
#pragma unroll
    for (int ks = 0; ks < 3; ks++){
      bf16x8 af0 = ar0[ks*4 + lq];
      bf16x8 af1 = ar1[ks*4 + lq];
#pragma unroll
      for (int nt = 0; nt < 4; nt++){
        bf16x8 bb = *(const bf16x8*)(W0bf + (nt*16 + lrow)*96 + ks*32 + lq*8);
        acc[0][nt] = __builtin_amdgcn_mfma_f32_16x16x32_bf16(af0, bb, acc[0][nt], 0, 0, 0);
        acc[1][nt] = __builtin_amdgcn_mfma_f32_16x16x32_bf16(af1, bb, acc[1][nt], 0, 0, 0);
      }
    }
#pragma unroll
    for (int nt = 0; nt < 4; nt++){
      float s = 0.f, s2 = 0.f;
#pragma unroll
      for (int mt = 0; mt < 2; mt++){
#pragma unroll
        for (int i = 0; i < 4; i++){
          float u = acc[mt][nt][i];
          s += u; s2 = fmaf(u, u, s2);
          int m = lw*32 + mt*16 + lq*4 + i;
          y0[(srow + m)*64 + nt*16 + lrow] = f2bf(u);
        }
      }
      s  += __shfl_xor(s, 16, 64);  s  += __shfl_xor(s, 32, 64);
      s2 += __shfl_xor(s2, 16, 64); s2 += __shfl_xor(s2, 32, 64);
      if (lane < 16){ atomicAdd(&sm.conv.lsum[nt*16 + lane], s); atomicAdd(&sm.conv.lsqr[nt*16 + lane], s2); }
    }
  }
  __syncthreads();
  if (t < 64){
    atomicAdd(&bsum0[(cb & 63)*128 + t], sm.conv.lsum[t]);
    atomicAdd(&bsqr0[(cb & 63)*128 + t], sm.conv.lsqr[t]);
  }
  __threadfence();
  __syncthreads();
  if (t == 0) arrive(&ctrs[1]);
  if (cb == 0){
    if (t == 0) waitc(&ctrs[1], NCB);
    __syncthreads();
    if (t < 64){
      float s = 0.f, s2 = 0.f;
      for (int k = 0; k < 64; k++){ s += bsum0[k*128 + t]; s2 += bsqr0[k*128 + t]; }
      const float inv = 1.f / (float)STOT;
      float m = s * inv, v = s2 * inv - m*m;
      float aa = g0v[t] / sqrtf(v + 1e-5f);
      a0[t] = aa; d0[t] = be0[t] - m*aa;
    }
    __threadfence();
    __syncthreads();
    if (t == 0) arrive(&ctrs[2]);
  }
  if (t == 0) waitc(&ctrs[2], 1);
  __syncthreads();

  // ---- P2: layer 1 (K=64 -> 128)
  if (t < 128){ sm.conv.lsum[t] = 0.f; sm.conv.lsqr[t] = 0.f; }
  if (t < 64){ sm.conv.av[t] = a0[t]; sm.conv.dv[t] = d0[t]; }
  __syncthreads();
  for (int j2 = Wk; j2 < 4096; j2 += NW){
    const size_t srow = (size_t)j2 * 128;
    const int m0 = lw*32 + lrow, m1 = m0 + 16;
    const u16* row0 = y0 + (srow + m0)*64;
    const u16* row1 = y0 + (srow + m1)*64;
    f32x4 acc[2][8];
#pragma unroll
    for (int mt = 0; mt < 2; mt++)
#pragma unroll
      for (int nt = 0; nt < 8; nt++){ f32x4 z = {0.f,0.f,0.f,0.f}; acc[mt][nt] = z; }
#pragma unroll
    for (int ks = 0; ks < 2; ks++){
      const int ko = ks*32 + lq*8;
      bf16x8 af0 = load_bn_relu(row0, ko, sm.conv.av, sm.conv.dv);
      bf16x8 af1 = load_bn_relu(row1, ko, sm.conv.av, sm.conv.dv);
#pragma unroll
      for (int nt = 0; nt < 8; nt++){
        bf16x8 bb = *(const bf16x8*)(W1bf + (nt*16 + lrow)*64 + ko);
        acc[0][nt] = __builtin_amdgcn_mfma_f32_16x16x32_bf16(af0, bb, acc[0][nt], 0, 0, 0);
        acc[1][nt] = __builtin_amdgcn_mfma_f32_16x16x32_bf16(af1, bb, acc[1][nt], 0, 0, 0);
      }
    }
#pragma unroll
    for (int nt = 0; nt < 8; nt++){
      float s = 0.f, s2 = 0.f;
#pragma unroll
      for (int mt = 0; mt < 2; mt++){
#pragma unroll
        for (int i = 0; i < 4; i++){
          float u = acc[mt][nt][i];
          s += u; s2 = fmaf(u, u, s2);
          int m = lw*32 + mt*16 + lq*4 + i;
          y1[(srow + m)*128 + nt*16 + lrow] = f2bf(u);
        }
      }
      s  += __shfl_xor(s, 16, 64);  s  += __shfl_xor(s, 32, 64);
      s2 += __shfl_xor(s2, 16, 64); s2 += __shfl_xor(s2, 32, 64);
      if (lane < 16){ atomicAdd(&sm.conv.lsum[nt*16 + lane], s); atomicAdd(&sm.conv.lsqr[nt*16 + lane], s2); }
    }
  }
  __syncthreads();
  if (t < 128){
    atomicAdd(&bsum1[(cb & 63)*128 + t], sm.conv.lsum[t]);
    atomicAdd(&bsqr1[(cb & 63)*128 + t], sm.conv.lsqr[t]);
  }
  __threadfence();
  __syncthreads();
  if (t == 0) arrive(&ctrs[3]);
  if (cb == 0){
    if (t == 0) waitc(&ctrs[3], NCB);
    __syncthreads();
    if (t < 128){
      float s = 0.f, s2 = 0.f;
      for (int k = 0; k < 64; k++){ s += bsum1[k*128 + t]; s2 += bsqr1[k*128 + t]; }
      const float inv = 1.f / (float)STOT;
      float m = s * inv, v = s2 * inv - m*m;
      float aa = g1v[t] / sqrtf(v + 1e-5f);
      a1[t] = aa; d1[t] = be1[t] - m*aa;
    }
    __threadfence();
    __syncthreads();
    if (t == 0) arrive(&ctrs[4]);
  }
  if (t == 0) waitc(&ctrs[4], 1);
  __syncthreads();

  // ---- P3: layer 2 (K=128 -> 128) + per-group max/min of pre-BN y2
  if (t < 128){ sm.conv.lsum[t] = 0.f; sm.conv.lsqr[t] = 0.f;
                sm.conv.av[t] = a1[t]; sm.conv.dv[t] = d1[t]; }
  __syncthreads();
  for (int j2 = Wk; j2 < 4096; j2 += NW){
    const size_t srow = (size_t)j2 * 128;
    const int m0 = lw*32 + lrow, m1 = m0 + 16;
    const u16* row0 = y1 + (srow + m0)*128;
    const u16* row1 = y1 + (srow + m1)*128;
    f32x4 acc[2][8];
#pragma unroll
    for (int mt = 0; mt < 2; mt++)
#pragma unroll
      for (int nt = 0; nt < 8; nt++){ f32x4 z = {0.f,0.f,0.f,0.f}; acc[mt][nt] = z; }
#pragma unroll
    for (int ks = 0; ks < 4; ks++){
      const int ko = ks*32 + lq*8;
      bf16x8 af0 = load_bn_relu(row0, ko, sm.conv.av, sm.conv.dv);
      bf16x8 af1 = load_bn_relu(row1, ko, sm.conv.av, sm.conv.dv);
#pragma unroll
      for (int nt = 0; nt < 8; nt++){
        bf16x8 bb = *(const bf16x8*)(W2bf + (nt*16 + lrow)*128 + ko);
        acc[0][nt] = __builtin_amdgcn_mfma_f32_16x16x32_bf16(af0, bb, acc[0][nt], 0, 0, 0);
        acc[1][nt] = __builtin_amdgcn_mfma_f32_16x16x32_bf16(af1, bb, acc[1][nt], 0, 0, 0);
      }
    }
#pragma unroll
    for (int nt = 0; nt < 8; nt++){
      float s = 0.f, s2 = 0.f, mx = -3.4e38f, mn = 3.4e38f;
#pragma unroll
      for (int mt = 0; mt < 2; mt++){
#pragma unroll
        for (int i = 0; i < 4; i++){
          float u = acc[mt][nt][i];
          s += u; s2 = fmaf(u, u, s2);
          mx = fmaxf(mx, u); mn = fminf(mn, u);
        }
      }
      s  += __shfl_xor(s, 16, 64);  s  += __shfl_xor(s, 32, 64);
      s2 += __shfl_xor(s2, 16, 64); s2 += __shfl_xor(s2, 32, 64);
      mx = fmaxf(mx, __shfl_xor(mx, 16, 64)); mx = fmaxf(mx, __shfl_xor(mx, 32, 64));
      mn = fminf(mn, __shfl_xor(mn, 16, 64)); mn = fminf(mn, __shfl_xor(mn, 32, 64));
      if (lane < 16){
        size_t gi = ((size_t)j2*4 + lw)*128 + nt*16 + lane;
        maxb[gi] = mx; minb[gi] = mn;
        atomicAdd(&sm.conv.lsum[nt*16 + lane], s); atomicAdd(&sm.conv.lsqr[nt*16 + lane], s2);
      }
    }
  }
  __syncthreads();
  if (t < 128){
    atomicAdd(&bsum2[(cb & 63)*128 + t], sm.conv.lsum[t]);
    atomicAdd(&bsqr2[(cb & 63)*128 + t], sm.conv.lsqr[t]);
  }
  __threadfence();
  __syncthreads();
  if (t == 0) arrive(&ctrs[5]);
  if (cb == 0){
    if (t == 0) waitc(&ctrs[5], NCB);
    __syncthreads();
    if (t < 128){
      float s = 0.f, s2 = 0.f;
      for (int k = 0; k < 64; k++){ s += bsum2[k*128 + t]; s2 += bsqr2[k*128 + t]; }
      const float inv = 1.f / (float)STOT;
      float m = s * inv, v = s2 * inv - m*m;
      float aa = g2v[t] / sqrtf(v + 1e-5f);
      a2[t] = aa; d2[t] = be2[t] - m*aa;
    }
    __threadfence();
    __syncthreads();
    if (t == 0) arrive(&ctrs[6]);
  }
  if (t == 0) waitc(&ctrs[6], 1);
  __syncthreads();

  // ---- P4: final BN2+relu on group max/min, store [B,128,NP] (np coalesced)
  for (u32 e = (u32)cb*1024u + t; e < 16u*1024u*128u; e += (u32)NCB*1024u){
    u32 np = e & 1023u;
    u32 c  = (e >> 10) & 127u;
    u32 b  = e >> 17;
    size_t gi = ((size_t)b*1024 + np)*128 + c;
    float a = a2[c];
    float v = (a >= 0.f) ? maxb[gi] : minb[gi];
    out1[((size_t)b*128 + c)*1024 + np] = fmaxf(fmaf(a, v, d2[c]), 0.f);
  }
}

// ---------------------------------------------------------------- launch
extern "C" void kernel_launch(void* const* d_in, const int* in_sizes, int n_in,
                              void* d_out, int out_size, void* d_ws, size_t ws_size,
                              hipStream_t stream) {
  const float* xyz    = (const float*)d_in[0];
  const float* points = (const float*)d_in[1];
  const int*   finit  = (const int*)d_in[2];
  const int*   gidx   = (const int*)d_in[3];
  const float* W0  = (const float*)d_in[4];
  const float* g0v = (const float*)d_in[6];
  const float* be0 = (const float*)d_in[7];
  const float* W1  = (const float*)d_in[8];
  const float* g1v = (const float*)d_in[10];
  const float* be1 = (const float*)d_in[11];
  const float* W2  = (const float*)d_in[12];
  const float* g2v = (const float*)d_in[14];
  const float* be2 = (const float*)d_in[15];

  float* out0 = (float*)d_out;
  float* out1 = out0 + 16*3*NPOINT;   // 49152

  char* ws = (char*)d_ws;
  // layout (bytes):
  //   [0, 128M)            y1 (l1 out); XP aliases [0,48M) (dead before l1 writes)
  //   [128M, 192M)         y0 (l0 out); maxb/minb alias (y0 dead after l1)
  //   [192M, ...)          statsF, W*bf, ctrs
  u16* y1 = (u16*)ws;
  u16* XP = (u16*)ws;
  u16* y0 = (u16*)(ws + 134217728);
  float* maxb = (float*)(ws + 134217728);
  float* minb = (float*)(ws + 134217728 + 8388608);
  float* statsF = (float*)(ws + 201326592);
  u16* W0bf = (u16*)(ws + 201326592 + 49920*4);          // 201526272
  u16* W1bf = W0bf + 64*96;
  u16* W2bf = W1bf + 128*64;
  u32* ctrs = (u32*)(ws + 205782016);                    // 64 u32

  zero_kernel<<<1, 64, 0, stream>>>(ctrs);
  mega_kernel<<<256, 1024, 0, stream>>>(
      xyz, points, finit, gidx,
      W0, g0v, be0, W1, g1v, be1, W2, g2v, be2,
      out0, out1, XP, y0, y1, maxb, minb, statsF,
      W0bf, W1bf, W2bf, ctrs);
}